// Round 1
// baseline (2430.059 us; speedup 1.0000x reference)
//
#include <hip/hip_runtime.h>
#include <stdint.h>

// ---- problem constants ----
#define T_DIM 100
#define B_DIM 1000
#define E_DIM 512
#define D_DIM 256
#define L_DIM 4
#define M_TOK (T_DIM * B_DIM)   // 100000 tokens
#define M_PAD 100096             // 782 * 128 (GEMM M padding; pad rows zeroed)
#define K_DIM 512

typedef unsigned short u16;
typedef __bf16 bf16x8 __attribute__((ext_vector_type(8)));
typedef float f32x4 __attribute__((ext_vector_type(4)));
typedef unsigned short ushort8 __attribute__((ext_vector_type(8)));

// bf16 <-> f32 helpers (RNE, finite inputs only)
__device__ __forceinline__ u16 f2bf(float f) {
  unsigned int u = __builtin_bit_cast(unsigned int, f);
  u += 0x7fffu + ((u >> 16) & 1u);
  return (u16)(u >> 16);
}
__device__ __forceinline__ float bf2f(u16 h) {
  unsigned int u = ((unsigned int)h) << 16;
  return __builtin_bit_cast(float, u);
}

// async global->LDS, 16B per lane; lds ptr must be wave-uniform
__device__ __forceinline__ void gld16(const u16* g, u16* l) {
  __builtin_amdgcn_global_load_lds(
      (const __attribute__((address_space(1))) unsigned int*)g,
      (__attribute__((address_space(3))) unsigned int*)l, 16, 0, 0);
}

// ---- transpose + cast weights: in fp32 (S, R, C) -> out bf16 (S, C, R) ----
__global__ void transpose_cast(const float* __restrict__ in, u16* __restrict__ out,
                               int R, int C) {
  __shared__ float t[32][33];
  const int s = blockIdx.z;
  const float* ib = in + (size_t)s * R * C;
  u16* ob = out + (size_t)s * R * C;
  const int c0 = blockIdx.x * 32, r0 = blockIdx.y * 32;
  const int tx = threadIdx.x, ty = threadIdx.y;  // (32, 8)
#pragma unroll
  for (int j = 0; j < 4; ++j)
    t[ty + j * 8][tx] = ib[(size_t)(r0 + ty + j * 8) * C + c0 + tx];
  __syncthreads();
#pragma unroll
  for (int j = 0; j < 4; ++j)
    ob[(size_t)(c0 + ty + j * 8) * R + r0 + tx] = f2bf(t[tx][ty + j * 8]);
}

// ---- fused LayerNorm + cast to bf16; zero-fills pad rows ----
__global__ __launch_bounds__(256) void ln_cast_kernel(
    const float* __restrict__ x, const float* __restrict__ g,
    const float* __restrict__ b, u16* __restrict__ out) {
  const int wid = threadIdx.x >> 6, lane = threadIdx.x & 63;
  const int row = blockIdx.x * 4 + wid;  // < M_PAD
  u16* orow = out + (size_t)row * E_DIM + lane * 8;
  if (row >= M_TOK) {
    ushort8 z = {0, 0, 0, 0, 0, 0, 0, 0};
    *(ushort8*)orow = z;
    return;
  }
  const float* xr = x + (size_t)row * E_DIM + lane * 8;
  const float4 a = *(const float4*)xr;
  const float4 c = *(const float4*)(xr + 4);
  float xe[8] = {a.x, a.y, a.z, a.w, c.x, c.y, c.z, c.w};
  float s = 0.f, q = 0.f;
#pragma unroll
  for (int u = 0; u < 8; ++u) { s += xe[u]; q += xe[u] * xe[u]; }
#pragma unroll
  for (int off = 32; off; off >>= 1) {
    s += __shfl_xor(s, off, 64);
    q += __shfl_xor(q, off, 64);
  }
  const float mean = s * (1.0f / 512.0f);
  const float var = q * (1.0f / 512.0f) - mean * mean;
  const float rstd = rsqrtf(var + 1e-5f);
  const float4 g0 = *(const float4*)(g + lane * 8);
  const float4 g1 = *(const float4*)(g + lane * 8 + 4);
  const float4 b0 = *(const float4*)(b + lane * 8);
  const float4 b1v = *(const float4*)(b + lane * 8 + 4);
  float ge[8] = {g0.x, g0.y, g0.z, g0.w, g1.x, g1.y, g1.z, g1.w};
  float be[8] = {b0.x, b0.y, b0.z, b0.w, b1v.x, b1v.y, b1v.z, b1v.w};
  ushort8 o;
#pragma unroll
  for (int u = 0; u < 8; ++u)
    o[u] = f2bf((xe[u] - mean) * rstd * ge[u] + be[u]);
  *(ushort8*)orow = o;
}

// ---- plain cast fp32 -> bf16 (head input); zero-fills pad rows ----
__global__ __launch_bounds__(256) void cast_kernel(const float* __restrict__ x,
                                                   u16* __restrict__ out) {
  const size_t idx = (size_t)blockIdx.x * 256 + threadIdx.x;
  const size_t e0 = idx * 8;
  const size_t row = e0 >> 9;
  ushort8 o;
  if (row >= M_TOK) {
    ushort8 z = {0, 0, 0, 0, 0, 0, 0, 0};
    o = z;
  } else {
    const float4 a = *(const float4*)(x + e0);
    const float4 c = *(const float4*)(x + e0 + 4);
    o[0] = f2bf(a.x); o[1] = f2bf(a.y); o[2] = f2bf(a.z); o[3] = f2bf(a.w);
    o[4] = f2bf(c.x); o[5] = f2bf(c.y); o[6] = f2bf(c.z); o[7] = f2bf(c.w);
  }
  *(ushort8*)(out + e0) = o;
}

// ---- bf16 MFMA GEMM: C[z] = A @ B[z]^T ----
// A: (M_PAD, 512) bf16 row-major; B: (z, N, 512) bf16 (transposed weights);
// C: (z, M_PAD, N) bf16. 128x128 tile, BK=32, 4 waves, 4x4 16x16 tiles/wave.
__global__ __launch_bounds__(256, 2) void gemm_bf16(
    const u16* __restrict__ A, const u16* __restrict__ B, u16* __restrict__ C,
    int N) {
  __shared__ u16 As[128 * 32];
  __shared__ u16 Bs[128 * 32];
  const int tid = threadIdx.x;
  const int wave = tid >> 6, lane = tid & 63;
  const int wm = wave >> 1, wn = wave & 1;
  const size_t m0 = (size_t)blockIdx.x * 128;
  const int n0 = blockIdx.y * 128;
  const int z = blockIdx.z;

  // staging addresses: wave w covers rows w*32..w*32+31, 2 instrs x 16 rows
  const u16* Ag = A + (m0 + wave * 32 + (lane >> 2)) * K_DIM + (lane & 3) * 8;
  const u16* Bg = B + ((size_t)z * N + n0 + wave * 32 + (lane >> 2)) * K_DIM +
                  (lane & 3) * 8;
  u16* Al = As + wave * 1024;
  u16* Bl = Bs + wave * 1024;

  f32x4 acc[4][4] = {};
  const int rA = lane & 15;
  const int ko = (lane >> 4) * 8;

  for (int kt = 0; kt < K_DIM; kt += 32) {
    gld16(Ag + kt, Al);
    gld16(Ag + kt + 16 * K_DIM, Al + 512);
    gld16(Bg + kt, Bl);
    gld16(Bg + kt + 16 * K_DIM, Bl + 512);
    __syncthreads();  // drains vmcnt before barrier

    bf16x8 af[4], bfr[4];
#pragma unroll
    for (int mi = 0; mi < 4; ++mi)
      af[mi] = *(const bf16x8*)&As[(wm * 64 + mi * 16 + rA) * 32 + ko];
#pragma unroll
    for (int ni = 0; ni < 4; ++ni)
      bfr[ni] = *(const bf16x8*)&Bs[(wn * 64 + ni * 16 + rA) * 32 + ko];
#pragma unroll
    for (int mi = 0; mi < 4; ++mi)
#pragma unroll
      for (int ni = 0; ni < 4; ++ni)
        acc[mi][ni] = __builtin_amdgcn_mfma_f32_16x16x32_bf16(
            af[mi], bfr[ni], acc[mi][ni], 0, 0, 0);
    __syncthreads();
  }

  u16* Cb = C + (size_t)z * M_PAD * N;
  const int rr = (lane >> 4) * 4;
  const int cc = lane & 15;
#pragma unroll
  for (int mi = 0; mi < 4; ++mi) {
#pragma unroll
    for (int ni = 0; ni < 4; ++ni) {
      const size_t row = m0 + wm * 64 + mi * 16 + rr;
      const int col = n0 + wn * 64 + ni * 16 + cc;
#pragma unroll
      for (int r = 0; r < 4; ++r)
        Cb[(row + r) * N + col] = f2bf(acc[mi][ni][r]);
    }
  }
}

// ---- SRU elementwise recurrence, one thread per (dir, b, d) ----
// U: (2, M_PAD, 1024) bf16, row m = t*B+b, col = gate*256 + d
// v, bb: layer slices (2, 2, 256) fp32. xout: (T, B, 512) fp32.
__global__ __launch_bounds__(256) void sru_scan(const u16* __restrict__ U,
                                                const float* __restrict__ v,
                                                const float* __restrict__ bb,
                                                float* __restrict__ xout) {
  const int d = threadIdx.x;       // 0..255
  const int b = blockIdx.x;        // 0..999
  const int dir = blockIdx.y;      // 0..1
  const float vf = v[(dir * 2 + 0) * 256 + d];
  const float vr = v[(dir * 2 + 1) * 256 + d];
  const float bf = bb[(dir * 2 + 0) * 256 + d];
  const float br = bb[(dir * 2 + 1) * 256 + d];
  const u16* Ud = U + (size_t)dir * M_PAD * 1024;
  float c = 0.f;
  for (int s = 0; s < T_DIM; ++s) {
    const int t = dir ? (T_DIM - 1 - s) : s;
    const size_t base = ((size_t)t * B_DIM + b) * 1024 + d;
    const float u0 = bf2f(Ud[base]);
    const float u1 = bf2f(Ud[base + 256]);
    const float u2 = bf2f(Ud[base + 512]);
    const float u3 = bf2f(Ud[base + 768]);
    const float f = 1.f / (1.f + __expf(-(u1 + vf * c + bf)));
    c = f * c + (1.f - f) * u0;
    const float r = 1.f / (1.f + __expf(-(u2 + vr * c + br)));
    const float h = r * c + (1.f - r) * u3;
    xout[((size_t)t * B_DIM + b) * 512 + dir * 256 + d] = h;
  }
}

// ---- head: bias + BN(eval) + ReLU + W2 + log_softmax, one wave per token ----
__global__ __launch_bounds__(256) void head_kernel(
    const u16* __restrict__ h, const float* __restrict__ b1,
    const float* __restrict__ bn_g, const float* __restrict__ bn_b,
    const float* __restrict__ bn_mean, const float* __restrict__ bn_var,
    const float* __restrict__ W2, const float* __restrict__ b2,
    float* __restrict__ out) {
  const int wid = threadIdx.x >> 6, lane = threadIdx.x & 63;
  const int row = blockIdx.x * 4 + wid;  // < 100000 (grid=25000)
  const u16* hr = h + (size_t)row * E_DIM + lane * 8;
  const ushort8 hv = *(const ushort8*)hr;
  float s0 = 0.f, s1 = 0.f, s2 = 0.f, s3 = 0.f;
  const int j0 = lane * 8;
#pragma unroll
  for (int u = 0; u < 8; ++u) {
    const int j = j0 + u;
    const float hb = bf2f(hv[u]) + b1[j];
    float hn = (hb - bn_mean[j]) * rsqrtf(bn_var[j] + 1e-5f) * bn_g[j] + bn_b[j];
    hn = fmaxf(hn, 0.f);
    const float4 w = *(const float4*)(W2 + j * 4);
    s0 += hn * w.x; s1 += hn * w.y; s2 += hn * w.z; s3 += hn * w.w;
  }
#pragma unroll
  for (int off = 32; off; off >>= 1) {
    s0 += __shfl_xor(s0, off, 64);
    s1 += __shfl_xor(s1, off, 64);
    s2 += __shfl_xor(s2, off, 64);
    s3 += __shfl_xor(s3, off, 64);
  }
  if (lane == 0) {
    const float4 bv = *(const float4*)b2;
    const float l0 = s0 + bv.x, l1 = s1 + bv.y, l2 = s2 + bv.z, l3 = s3 + bv.w;
    const float mx = fmaxf(fmaxf(l0, l1), fmaxf(l2, l3));
    const float lse =
        mx + logf(__expf(l0 - mx) + __expf(l1 - mx) + __expf(l2 - mx) + __expf(l3 - mx));
    float4 o = {l0 - lse, l1 - lse, l2 - lse, l3 - lse};
    *(float4*)(out + (size_t)row * 4) = o;
  }
}

extern "C" void kernel_launch(void* const* d_in, const int* in_sizes, int n_in,
                              void* d_out, int out_size, void* d_ws, size_t ws_size,
                              hipStream_t stream) {
  const float* sentence = (const float*)d_in[0];
  const float* sru_W = (const float*)d_in[1];
  const float* sru_v = (const float*)d_in[2];
  const float* sru_b = (const float*)d_in[3];
  const float* ln_g = (const float*)d_in[4];
  const float* ln_b = (const float*)d_in[5];
  const float* W1 = (const float*)d_in[6];
  const float* b1 = (const float*)d_in[7];
  const float* bn_g = (const float*)d_in[8];
  const float* bn_b = (const float*)d_in[9];
  const float* bn_mean = (const float*)d_in[10];
  const float* bn_var = (const float*)d_in[11];
  const float* W2 = (const float*)d_in[12];
  const float* b2 = (const float*)d_in[13];

  // workspace layout (726,204,416 bytes total)
  char* ws = (char*)d_ws;
  const size_t X_OFF = 0;                                   // fp32 x: 204,800,000
  const size_t XL_OFF = X_OFF + (size_t)M_TOK * 512 * 4;    // bf16 xl: 102,498,304
  const size_t U_OFF = XL_OFF + (size_t)M_PAD * 512 * 2;    // bf16 U: 409,993,216
  const size_t WT_OFF = U_OFF + (size_t)2 * M_PAD * 1024 * 2;  // bf16 WT: 8,388,608
  const size_t W1T_OFF = WT_OFF + (size_t)8 * 512 * 1024 * 2;  // bf16 W1T: 524,288
  float* x_buf = (float*)(ws + X_OFF);
  u16* xl = (u16*)(ws + XL_OFF);
  u16* U = (u16*)(ws + U_OFF);
  u16* WT = (u16*)(ws + WT_OFF);
  u16* W1T = (u16*)(ws + W1T_OFF);
  u16* hbuf = U;  // head GEMM output aliases U (dead by then)

  // weights -> bf16 transposed (N, K)
  transpose_cast<<<dim3(32, 16, 8), dim3(32, 8), 0, stream>>>(sru_W, WT, 512, 1024);
  transpose_cast<<<dim3(16, 16, 1), dim3(32, 8), 0, stream>>>(W1, W1T, 512, 512);

  for (int l = 0; l < L_DIM; ++l) {
    const float* xin = (l == 0) ? sentence : x_buf;
    ln_cast_kernel<<<M_PAD / 4, 256, 0, stream>>>(xin, ln_g + l * 512,
                                                  ln_b + l * 512, xl);
    gemm_bf16<<<dim3(M_PAD / 128, 1024 / 128, 2), 256, 0, stream>>>(
        xl, WT + (size_t)l * 2 * 1024 * 512, U, 1024);
    sru_scan<<<dim3(1000, 2), 256, 0, stream>>>(U, sru_v + l * 1024,
                                                sru_b + l * 1024, x_buf);
  }
  cast_kernel<<<M_PAD * 512 / 8 / 256, 256, 0, stream>>>(x_buf, xl);
  gemm_bf16<<<dim3(M_PAD / 128, 512 / 128, 1), 256, 0, stream>>>(xl, W1T, hbuf, 512);
  head_kernel<<<M_TOK / 4, 256, 0, stream>>>(hbuf, b1, bn_g, bn_b, bn_mean,
                                             bn_var, W2, b2, (float*)d_out);
}

// Round 2
// 2220.356 us; speedup vs baseline: 1.0944x; 1.0944x over previous
//
#include <hip/hip_runtime.h>
#include <stdint.h>

// ---- problem constants ----
#define T_DIM 100
#define B_DIM 1000
#define E_DIM 512
#define D_DIM 256
#define L_DIM 4
#define M_TOK (T_DIM * B_DIM)   // 100000 tokens
#define M_PAD 100096             // 782 * 128 (GEMM M padding; pad rows zeroed)
#define K_DIM 512

typedef unsigned short u16;
typedef __bf16 bf16x8 __attribute__((ext_vector_type(8)));
typedef float f32x4 __attribute__((ext_vector_type(4)));
typedef unsigned short ushort8 __attribute__((ext_vector_type(8)));

__device__ __forceinline__ u16 f2bf(float f) {
  unsigned int u = __builtin_bit_cast(unsigned int, f);
  u += 0x7fffu + ((u >> 16) & 1u);
  return (u16)(u >> 16);
}
__device__ __forceinline__ float bf2f(u16 h) {
  unsigned int u = ((unsigned int)h) << 16;
  return __builtin_bit_cast(float, u);
}

__device__ __forceinline__ void gld16(const u16* g, u16* l) {
  __builtin_amdgcn_global_load_lds(
      (const __attribute__((address_space(1))) unsigned int*)g,
      (__attribute__((address_space(3))) unsigned int*)l, 16, 0, 0);
}

// ---- transpose + cast weights: in fp32 (S, R, C) -> out bf16 (S, C, R) ----
__global__ void transpose_cast(const float* __restrict__ in, u16* __restrict__ out,
                               int R, int C) {
  __shared__ float t[32][33];
  const int s = blockIdx.z;
  const float* ib = in + (size_t)s * R * C;
  u16* ob = out + (size_t)s * R * C;
  const int c0 = blockIdx.x * 32, r0 = blockIdx.y * 32;
  const int tx = threadIdx.x, ty = threadIdx.y;  // (32, 8)
#pragma unroll
  for (int j = 0; j < 4; ++j)
    t[ty + j * 8][tx] = ib[(size_t)(r0 + ty + j * 8) * C + c0 + tx];
  __syncthreads();
#pragma unroll
  for (int j = 0; j < 4; ++j)
    ob[(size_t)(c0 + ty + j * 8) * R + r0 + tx] = f2bf(t[tx][ty + j * 8]);
}

// ---- zero GEMM pad rows of xl (rows M_TOK..M_PAD-1), once per call ----
__global__ __launch_bounds__(256) void zero_pad(u16* __restrict__ xl) {
  const int i = blockIdx.x * 256 + threadIdx.x;  // 6144 lanes x 8 elems
  ushort8 z = {0, 0, 0, 0, 0, 0, 0, 0};
  *(ushort8*)(xl + (size_t)M_TOK * 512 + (size_t)i * 8) = z;
}

// ---- fused LayerNorm + cast to bf16 (rows < M_TOK only) ----
template <typename TI>
__global__ __launch_bounds__(256) void ln_cast_kernel(
    const TI* __restrict__ x, const float* __restrict__ g,
    const float* __restrict__ b, u16* __restrict__ out) {
  const int wid = threadIdx.x >> 6, lane = threadIdx.x & 63;
  const int row = blockIdx.x * 4 + wid;  // < M_TOK
  float xe[8];
  if constexpr (sizeof(TI) == 4) {
    const float* xr = (const float*)x + (size_t)row * E_DIM + lane * 8;
    const float4 a = *(const float4*)xr;
    const float4 c = *(const float4*)(xr + 4);
    xe[0] = a.x; xe[1] = a.y; xe[2] = a.z; xe[3] = a.w;
    xe[4] = c.x; xe[5] = c.y; xe[6] = c.z; xe[7] = c.w;
  } else {
    const u16* xr = (const u16*)x + (size_t)row * E_DIM + lane * 8;
    const ushort8 hv = *(const ushort8*)xr;
#pragma unroll
    for (int u = 0; u < 8; ++u) xe[u] = bf2f(hv[u]);
  }
  float s = 0.f, q = 0.f;
#pragma unroll
  for (int u = 0; u < 8; ++u) { s += xe[u]; q += xe[u] * xe[u]; }
#pragma unroll
  for (int off = 32; off; off >>= 1) {
    s += __shfl_xor(s, off, 64);
    q += __shfl_xor(q, off, 64);
  }
  const float mean = s * (1.0f / 512.0f);
  const float var = q * (1.0f / 512.0f) - mean * mean;
  const float rstd = rsqrtf(var + 1e-5f);
  const float4 g0 = *(const float4*)(g + lane * 8);
  const float4 g1 = *(const float4*)(g + lane * 8 + 4);
  const float4 b0 = *(const float4*)(b + lane * 8);
  const float4 b1v = *(const float4*)(b + lane * 8 + 4);
  float ge[8] = {g0.x, g0.y, g0.z, g0.w, g1.x, g1.y, g1.z, g1.w};
  float be[8] = {b0.x, b0.y, b0.z, b0.w, b1v.x, b1v.y, b1v.z, b1v.w};
  ushort8 o;
#pragma unroll
  for (int u = 0; u < 8; ++u)
    o[u] = f2bf((xe[u] - mean) * rstd * ge[u] + be[u]);
  *(ushort8*)(out + (size_t)row * E_DIM + lane * 8) = o;
}

// ---- bf16 MFMA GEMM: C[z] = A @ B[z]^T ----
// Grid: x = (z * ntil + ntile)  [16 consecutive blocks share one A m-tile],
//       y = m-tile. 128x128 tile, BK=32, 4 waves, 4x4 16x16 tiles/wave.
// LDS chunk XOR-swizzle: chunk c of row r stored at position c ^ ((r>>1)&3)
// -> 2-way (free) bank aliasing on ds_read_b128 instead of 8-way.
__global__ __launch_bounds__(256, 4) void gemm_bf16(
    const u16* __restrict__ A, const u16* __restrict__ B, u16* __restrict__ C,
    int N, int ntil_shift) {
  __shared__ u16 As[128 * 32];
  __shared__ u16 Bs[128 * 32];
  const int tid = threadIdx.x;
  const int wave = tid >> 6, lane = tid & 63;
  const int wm = wave >> 1, wn = wave & 1;
  const int nz = blockIdx.x;
  const int z = nz >> ntil_shift;
  const int n0 = (nz & ((1 << ntil_shift) - 1)) << 7;
  const size_t m0 = (size_t)blockIdx.y * 128;

  // staging: lane l covers row (l>>2); loads data chunk (l&3)^((l>>3)&3)
  // which lands at stored position (l&3) = p, satisfying data(p) = p ^ f(row).
  const int c_ld = (lane & 3) ^ ((lane >> 3) & 3);
  const u16* Ag = A + (m0 + wave * 32 + (lane >> 2)) * K_DIM + c_ld * 8;
  const u16* Bg = B + ((size_t)z * N + n0 + wave * 32 + (lane >> 2)) * K_DIM +
                  c_ld * 8;
  u16* Al = As + wave * 1024;
  u16* Bl = Bs + wave * 1024;

  f32x4 acc[4][4] = {};
  const int rA = lane & 15;
  const int ch = lane >> 4;                       // data chunk 0..3
  const int sw = (ch ^ ((rA >> 1) & 3)) * 8;      // swizzled element offset

  for (int kt = 0; kt < K_DIM; kt += 32) {
    gld16(Ag + kt, Al);
    gld16(Ag + kt + 16 * K_DIM, Al + 512);
    gld16(Bg + kt, Bl);
    gld16(Bg + kt + 16 * K_DIM, Bl + 512);
    __syncthreads();

    bf16x8 af[4], bfr[4];
#pragma unroll
    for (int mi = 0; mi < 4; ++mi)
      af[mi] = *(const bf16x8*)&As[(wm * 64 + mi * 16 + rA) * 32 + sw];
#pragma unroll
    for (int ni = 0; ni < 4; ++ni)
      bfr[ni] = *(const bf16x8*)&Bs[(wn * 64 + ni * 16 + rA) * 32 + sw];
#pragma unroll
    for (int mi = 0; mi < 4; ++mi)
#pragma unroll
      for (int ni = 0; ni < 4; ++ni)
        acc[mi][ni] = __builtin_amdgcn_mfma_f32_16x16x32_bf16(
            af[mi], bfr[ni], acc[mi][ni], 0, 0, 0);
    __syncthreads();
  }

  u16* Cb = C + (size_t)z * M_PAD * N;
  const int rr = (lane >> 4) * 4;
  const int cc = lane & 15;
#pragma unroll
  for (int mi = 0; mi < 4; ++mi) {
#pragma unroll
    for (int ni = 0; ni < 4; ++ni) {
      const size_t row = m0 + wm * 64 + mi * 16 + rr;
      const int col = n0 + wn * 64 + ni * 16 + cc;
#pragma unroll
      for (int r = 0; r < 4; ++r)
        Cb[(row + r) * N + col] = f2bf(acc[mi][ni][r]);
    }
  }
}

// ---- SRU elementwise recurrence, one thread per (dir, b, d); bf16 out ----
__global__ __launch_bounds__(256) void sru_scan(const u16* __restrict__ U,
                                                const float* __restrict__ v,
                                                const float* __restrict__ bb,
                                                u16* __restrict__ xout) {
  const int d = threadIdx.x;       // 0..255
  const int b = blockIdx.x;        // 0..999
  const int dir = blockIdx.y;      // 0..1
  const float vf = v[(dir * 2 + 0) * 256 + d];
  const float vr = v[(dir * 2 + 1) * 256 + d];
  const float bf = bb[(dir * 2 + 0) * 256 + d];
  const float br = bb[(dir * 2 + 1) * 256 + d];
  const u16* Ud = U + (size_t)dir * M_PAD * 1024;
  float c = 0.f;
  for (int s = 0; s < T_DIM; ++s) {
    const int t = dir ? (T_DIM - 1 - s) : s;
    const size_t base = ((size_t)t * B_DIM + b) * 1024 + d;
    const float u0 = bf2f(Ud[base]);
    const float u1 = bf2f(Ud[base + 256]);
    const float u2 = bf2f(Ud[base + 512]);
    const float u3 = bf2f(Ud[base + 768]);
    const float f = 1.f / (1.f + __expf(-(u1 + vf * c + bf)));
    c = f * c + (1.f - f) * u0;
    const float r = 1.f / (1.f + __expf(-(u2 + vr * c + br)));
    const float h = r * c + (1.f - r) * u3;
    xout[((size_t)t * B_DIM + b) * 512 + dir * 256 + d] = f2bf(h);
  }
}

// ---- head: bias + BN(eval) + ReLU + W2 + log_softmax, one wave per token ----
__global__ __launch_bounds__(256) void head_kernel(
    const u16* __restrict__ h, const float* __restrict__ b1,
    const float* __restrict__ bn_g, const float* __restrict__ bn_b,
    const float* __restrict__ bn_mean, const float* __restrict__ bn_var,
    const float* __restrict__ W2, const float* __restrict__ b2,
    float* __restrict__ out) {
  const int wid = threadIdx.x >> 6, lane = threadIdx.x & 63;
  const int row = blockIdx.x * 4 + wid;  // < 100000 (grid=25000)
  const u16* hr = h + (size_t)row * E_DIM + lane * 8;
  const ushort8 hv = *(const ushort8*)hr;
  float s0 = 0.f, s1 = 0.f, s2 = 0.f, s3 = 0.f;
  const int j0 = lane * 8;
#pragma unroll
  for (int u = 0; u < 8; ++u) {
    const int j = j0 + u;
    const float hb = bf2f(hv[u]) + b1[j];
    float hn = (hb - bn_mean[j]) * rsqrtf(bn_var[j] + 1e-5f) * bn_g[j] + bn_b[j];
    hn = fmaxf(hn, 0.f);
    const float4 w = *(const float4*)(W2 + j * 4);
    s0 += hn * w.x; s1 += hn * w.y; s2 += hn * w.z; s3 += hn * w.w;
  }
#pragma unroll
  for (int off = 32; off; off >>= 1) {
    s0 += __shfl_xor(s0, off, 64);
    s1 += __shfl_xor(s1, off, 64);
    s2 += __shfl_xor(s2, off, 64);
    s3 += __shfl_xor(s3, off, 64);
  }
  if (lane == 0) {
    const float4 bv = *(const float4*)b2;
    const float l0 = s0 + bv.x, l1 = s1 + bv.y, l2 = s2 + bv.z, l3 = s3 + bv.w;
    const float mx = fmaxf(fmaxf(l0, l1), fmaxf(l2, l3));
    const float lse =
        mx + logf(__expf(l0 - mx) + __expf(l1 - mx) + __expf(l2 - mx) + __expf(l3 - mx));
    float4 o = {l0 - lse, l1 - lse, l2 - lse, l3 - lse};
    *(float4*)(out + (size_t)row * 4) = o;
  }
}

extern "C" void kernel_launch(void* const* d_in, const int* in_sizes, int n_in,
                              void* d_out, int out_size, void* d_ws, size_t ws_size,
                              hipStream_t stream) {
  const float* sentence = (const float*)d_in[0];
  const float* sru_W = (const float*)d_in[1];
  const float* sru_v = (const float*)d_in[2];
  const float* sru_b = (const float*)d_in[3];
  const float* ln_g = (const float*)d_in[4];
  const float* ln_b = (const float*)d_in[5];
  const float* W1 = (const float*)d_in[6];
  const float* b1 = (const float*)d_in[7];
  const float* bn_g = (const float*)d_in[8];
  const float* bn_b = (const float*)d_in[9];
  const float* bn_mean = (const float*)d_in[10];
  const float* bn_var = (const float*)d_in[11];
  const float* W2 = (const float*)d_in[12];
  const float* b2 = (const float*)d_in[13];

  // workspace layout (~624 MB)
  char* ws = (char*)d_ws;
  const size_t XL_OFF = 0;                                   // bf16 xl: 102,498,304
  const size_t X_OFF = XL_OFF + (size_t)M_PAD * 512 * 2;     // bf16 x:  102,400,000
  const size_t U_OFF = X_OFF + (size_t)M_TOK * 512 * 2;      // bf16 U:  409,993,216
  const size_t WT_OFF = U_OFF + (size_t)2 * M_PAD * 1024 * 2;   // bf16 WT: 8,388,608
  const size_t W1T_OFF = WT_OFF + (size_t)8 * 512 * 1024 * 2;   // bf16 W1T: 524,288
  u16* xl = (u16*)(ws + XL_OFF);
  u16* x_buf = (u16*)(ws + X_OFF);
  u16* U = (u16*)(ws + U_OFF);
  u16* WT = (u16*)(ws + WT_OFF);
  u16* W1T = (u16*)(ws + W1T_OFF);
  u16* hbuf = U;  // head GEMM output aliases U (dead by then)

  // weights -> bf16 transposed (N, K); zero xl pad rows once
  transpose_cast<<<dim3(32, 16, 8), dim3(32, 8), 0, stream>>>(sru_W, WT, 512, 1024);
  transpose_cast<<<dim3(16, 16, 1), dim3(32, 8), 0, stream>>>(W1, W1T, 512, 512);
  zero_pad<<<24, 256, 0, stream>>>(xl);

  for (int l = 0; l < L_DIM; ++l) {
    if (l == 0)
      ln_cast_kernel<float><<<M_TOK / 4, 256, 0, stream>>>(
          sentence, ln_g, ln_b, xl);
    else
      ln_cast_kernel<u16><<<M_TOK / 4, 256, 0, stream>>>(
          x_buf, ln_g + l * 512, ln_b + l * 512, xl);
    gemm_bf16<<<dim3(16, M_PAD / 128), 256, 0, stream>>>(
        xl, WT + (size_t)l * 2 * 1024 * 512, U, 1024, 3);
    // layer 3's scan output is the head input (no LN) -> write xl directly
    u16* xo = (l == L_DIM - 1) ? xl : x_buf;
    sru_scan<<<dim3(1000, 2), 256, 0, stream>>>(U, sru_v + l * 1024,
                                                sru_b + l * 1024, xo);
  }
  gemm_bf16<<<dim3(4, M_PAD / 128), 256, 0, stream>>>(xl, W1T, hbuf, 512, 2);
  head_kernel<<<M_TOK / 4, 256, 0, stream>>>(hbuf, b1, bn_g, bn_b, bn_mean,
                                             bn_var, W2, b2, (float*)d_out);
}